// Round 1
// baseline (631.328 us; speedup 1.0000x reference)
//
#include <hip/hip_runtime.h>
#include <hip/hip_bf16.h>

// Problem constants
#define BS  32
#define N   1024
#define DIM 1024

typedef unsigned short u16;
typedef unsigned int   u32;

typedef __attribute__((ext_vector_type(8))) __bf16 bf16x8;
typedef __attribute__((ext_vector_type(4))) float  f32x4;

__device__ __forceinline__ u16 f2bf(float f) {
    u32 u = __builtin_bit_cast(u32, f);
    u = (u + 0x7FFF + ((u >> 16) & 1)) >> 16;   // RNE, finite inputs only
    return (u16)u;
}

__device__ __forceinline__ void async16(const u16* g, u16* l) {
    __builtin_amdgcn_global_load_lds(
        (const __attribute__((address_space(1))) u32*)g,
        (__attribute__((address_space(3))) u32*)l,
        16, 0, 0);
}

// ---------------------------------------------------------------------------
// K1: convert x (and Wv) to bf16, fused with q = x.Wq+bq, k = x.Wk+bk.
// One wave per 1024-elem row. Rows [0, BS*N) are x rows; [BS*N, BS*N+DIM) are Wv.
__global__ void convert_qk(const float* __restrict__ x,
                           const float* __restrict__ Wq, const float* __restrict__ bq,
                           const float* __restrict__ Wk, const float* __restrict__ bk,
                           const float* __restrict__ Wv,
                           u16* __restrict__ xb, u16* __restrict__ Wvb,
                           float* __restrict__ qv, float* __restrict__ kv)
{
    int gw   = (blockIdx.x * 256 + threadIdx.x) >> 6;
    int lane = threadIdx.x & 63;
    bool isX = gw < BS * N;
    const float* src = isX ? (x + (size_t)gw * DIM) : (Wv + (size_t)(gw - BS * N) * DIM);
    u16*         dst = isX ? (xb + (size_t)gw * DIM) : (Wvb + (size_t)(gw - BS * N) * DIM);
    float qd = 0.f, kd = 0.f;
    #pragma unroll
    for (int i = 0; i < 4; ++i) {
        int e = i * 256 + lane * 4;
        float4 xv = *(const float4*)&src[e];
        uint2 p;
        p.x = (u32)f2bf(xv.x) | ((u32)f2bf(xv.y) << 16);
        p.y = (u32)f2bf(xv.z) | ((u32)f2bf(xv.w) << 16);
        *(uint2*)&dst[e] = p;
        if (isX) {
            float4 wq = *(const float4*)&Wq[e];
            float4 wk = *(const float4*)&Wk[e];
            qd += xv.x * wq.x + xv.y * wq.y + xv.z * wq.z + xv.w * wq.w;
            kd += xv.x * wk.x + xv.y * wk.y + xv.z * wk.z + xv.w * wk.w;
        }
    }
    if (isX) {
        #pragma unroll
        for (int off = 32; off; off >>= 1) {
            qd += __shfl_xor(qd, off);
            kd += __shfl_xor(kd, off);
        }
        if (lane == 0) { qv[gw] = qd + bq[0]; kv[gw] = kd + bk[0]; }
    }
}

// ---------------------------------------------------------------------------
// K2: invZ[b,i] = 1 / sum_j exp(q_i * k_j). One wave per row.
__global__ void zker(const float* __restrict__ qv, const float* __restrict__ kv,
                     float* __restrict__ invZ)
{
    int gw   = (blockIdx.x * 256 + threadIdx.x) >> 6;   // 0..BS*N-1
    int lane = threadIdx.x & 63;
    int b    = gw >> 10;
    float qi = qv[gw];
    const float* kr = kv + (size_t)b * N;
    float z = 0.f;
    #pragma unroll
    for (int i = 0; i < 4; ++i) {
        int e = i * 256 + lane * 4;
        float4 kk = *(const float4*)&kr[e];
        z += __expf(qi * kk.x) + __expf(qi * kk.y) + __expf(qi * kk.z) + __expf(qi * kk.w);
    }
    #pragma unroll
    for (int off = 32; off; off >>= 1) z += __shfl_xor(z, off);
    if (lane == 0) invZ[gw] = 1.0f / z;
}

// ---------------------------------------------------------------------------
// K3: attention tiles. 64x64 tile per block.
// Phase 1: fp32 attention to d_out (row-major, coalesced).
// Phase 2: recompute exp with transposed mapping, write bf16 aT[m][n]=attn[n][m].
__global__ void attker(const float* __restrict__ qv, const float* __restrict__ kv,
                       const float* __restrict__ invZ,
                       float* __restrict__ att, u16* __restrict__ aT)
{
    int bid = blockIdx.x;
    int b   = bid >> 8;
    int t   = bid & 255;
    int i0  = (t >> 4) * 64, j0 = (t & 15) * 64;
    __shared__ float sq[64], siz[64], sk[64];
    int tid = threadIdx.x;
    if (tid < 64)        sq[tid]        = qv[b * N + i0 + tid];
    else if (tid < 128)  siz[tid - 64]  = invZ[b * N + i0 + (tid - 64)];
    else if (tid < 192)  sk[tid - 128]  = kv[b * N + j0 + (tid - 128)];
    __syncthreads();
    float* ab = att + (size_t)b * N * N;
    u16*   tb = aT  + (size_t)b * N * N;
    #pragma unroll 4
    for (int s = 0; s < 16; ++s) {              // phase 1: c fastest
        int idx = s * 256 + tid;
        int r = idx >> 6, c = idx & 63;
        float a = __expf(sq[r] * sk[c]) * siz[r];
        ab[(size_t)(i0 + r) * N + j0 + c] = a;
    }
    #pragma unroll 4
    for (int s = 0; s < 16; ++s) {              // phase 2: r fastest
        int idx = s * 256 + tid;
        int c = idx >> 6, r = idx & 63;
        float a = __expf(sq[r] * sk[c]) * siz[r];
        tb[(size_t)(j0 + c) * N + i0 + r] = f2bf(a);
    }
}

// ---------------------------------------------------------------------------
// K4/K5: C[b] = A[b] (MxK row-major) @ B[b]^T (B stored NxK row-major) [+ bias]
// M=Nc=K=1024. 128x128 C-tile per 256-thread block, BK=32, mfma 16x16x32 bf16.
// m97 structure: global_load_lds width-16 staging, 2 barriers per K-iter.
template<int BF16OUT, int BIAS>
__global__ __launch_bounds__(256) void gemm_bt(
    const u16* __restrict__ A, size_t aBatch,
    const u16* __restrict__ B, size_t bBatch,
    void* __restrict__ C, size_t cBatch,
    const float* __restrict__ bias)
{
    const int K = 1024, LD = 1024;
    int blk = blockIdx.x;
    int b   = blk >> 6;
    int t   = blk & 63;
    int m0  = (t >> 3) * 128, n0 = (t & 7) * 128;
    const u16* Ab = A + aBatch * (size_t)b;
    const u16* Bb = B + bBatch * (size_t)b;
    __shared__ u16 lA[128 * 32];
    __shared__ u16 lB[128 * 32];
    int w = threadIdx.x >> 6, lane = threadIdx.x & 63;
    int wr = (w >> 1) * 64, wc = (w & 1) * 64;
    int rowl = lane >> 2;             // 0..15 within 16-row chunk
    int col8 = (lane & 3) * 8;        // u16 offset in K
    int frow = lane & 15, fk = (lane >> 4) * 8;
    f32x4 acc[4][4] = {};

    for (int k0 = 0; k0 < K; k0 += 32) {
        #pragma unroll
        for (int s = 0; s < 2; ++s) {
            int rr = (s * 4 + w) * 16;
            const u16* ga = Ab + (size_t)(m0 + rr + rowl) * LD + k0 + col8;
            const u16* gb = Bb + (size_t)(n0 + rr + rowl) * LD + k0 + col8;
            async16(ga, &lA[rr * 32]);
            async16(gb, &lB[rr * 32]);
        }
        __syncthreads();
        bf16x8 af[4], bfr[4];
        #pragma unroll
        for (int i = 0; i < 4; ++i)
            af[i] = *(const bf16x8*)&lA[(wr + i * 16 + frow) * 32 + fk];
        #pragma unroll
        for (int j = 0; j < 4; ++j)
            bfr[j] = *(const bf16x8*)&lB[(wc + j * 16 + frow) * 32 + fk];
        #pragma unroll
        for (int i = 0; i < 4; ++i)
            #pragma unroll
            for (int j = 0; j < 4; ++j)
                acc[i][j] = __builtin_amdgcn_mfma_f32_16x16x32_bf16(af[i], bfr[j], acc[i][j], 0, 0, 0);
        __syncthreads();
    }

    int r4 = (lane >> 4) * 4, cc = lane & 15;
    #pragma unroll
    for (int i = 0; i < 4; ++i) {
        #pragma unroll
        for (int j = 0; j < 4; ++j) {
            #pragma unroll
            for (int rg = 0; rg < 4; ++rg) {
                int row = m0 + wr + i * 16 + r4 + rg;
                int col = n0 + wc + j * 16 + cc;
                float v = acc[i][j][rg];
                if (BIAS) v += bias[row];
                if (BF16OUT)
                    ((u16*)C + cBatch * (size_t)b)[(size_t)row * LD + col] = f2bf(v);
                else
                    ((float*)C + cBatch * (size_t)b)[(size_t)row * LD + col] = v;
            }
        }
    }
}

// ---------------------------------------------------------------------------
extern "C" void kernel_launch(void* const* d_in, const int* in_sizes, int n_in,
                              void* d_out, int out_size, void* d_ws, size_t ws_size,
                              hipStream_t stream)
{
    const float* x  = (const float*)d_in[0];
    const float* Wq = (const float*)d_in[1];
    const float* bq = (const float*)d_in[2];
    const float* Wk = (const float*)d_in[3];
    const float* bk = (const float*)d_in[4];
    const float* Wv = (const float*)d_in[5];
    const float* bv = (const float*)d_in[6];

    float* out = (float*)d_out;                 // (bs, n, d) raw-reshape of (bs, d, n)
    float* att = out + (size_t)BS * N * N;      // (bs, n, n)

    // Workspace layout (~195 MiB):
    char* ws = (char*)d_ws;
    u16*  xb   = (u16*)ws;                         // BS*N*DIM bf16
    u16*  vb   = xb + (size_t)BS * N * DIM;        // BS*DIM*N bf16  (v, row-major d x n)
    u16*  aT   = vb + (size_t)BS * N * DIM;        // BS*N*N bf16    (attn^T, m x n)
    u16*  Wvb  = aT + (size_t)BS * N * N;          // DIM*DIM bf16
    float* qv  = (float*)(Wvb + (size_t)DIM * DIM);
    float* kv  = qv + BS * N;
    float* invZ = kv + BS * N;

    convert_qk<<<(BS * N + DIM) / 4, 256, 0, stream>>>(x, Wq, bq, Wk, bk, Wv, xb, Wvb, qv, kv);
    zker<<<(BS * N) / 4, 256, 0, stream>>>(qv, kv, invZ);
    attker<<<BS * 256, 256, 0, stream>>>(qv, kv, invZ, att, aT);
    // v[b] = Wv @ x[b]^T + bv : A=Wvb (shared), B=xb[b], C=vb[b] (bf16)
    gemm_bt<1, 1><<<BS * 64, 256, 0, stream>>>(Wvb, 0, xb, (size_t)N * DIM, vb, (size_t)N * DIM, bv);
    // out[b] = v[b] @ attn[b] : A=vb[b], B=aT[b] (attn^T), C=out[b] (fp32)
    gemm_bt<0, 0><<<BS * 64, 256, 0, stream>>>(vb, (size_t)N * DIM, aT, (size_t)N * N, out, (size_t)N * N, nullptr);
}

// Round 2
// 596.023 us; speedup vs baseline: 1.0592x; 1.0592x over previous
//
#include <hip/hip_runtime.h>
#include <hip/hip_bf16.h>

// Problem constants
#define BS  32
#define N   1024
#define DIM 1024

typedef unsigned short u16;
typedef unsigned int   u32;

typedef __attribute__((ext_vector_type(8))) __bf16 bf16x8;
typedef __attribute__((ext_vector_type(4))) float  f32x4;

__device__ __forceinline__ u16 f2bf(float f) {
    u32 u = __builtin_bit_cast(u32, f);
    u = (u + 0x7FFF + ((u >> 16) & 1)) >> 16;   // RNE, finite inputs only
    return (u16)u;
}

__device__ __forceinline__ void async16(const u16* g, u16* l) {
    __builtin_amdgcn_global_load_lds(
        (const __attribute__((address_space(1))) u32*)g,
        (__attribute__((address_space(3))) u32*)l,
        16, 0, 0);
}

// ---------------------------------------------------------------------------
// K1: convert x (and Wv) to bf16, fused with q = x.Wq+bq, k = x.Wk+bk.
// One wave per 1024-elem row. Rows [0, BS*N) are x rows; [BS*N, BS*N+DIM) are Wv.
__global__ void convert_qk(const float* __restrict__ x,
                           const float* __restrict__ Wq, const float* __restrict__ bq,
                           const float* __restrict__ Wk, const float* __restrict__ bk,
                           const float* __restrict__ Wv,
                           u16* __restrict__ xb, u16* __restrict__ Wvb,
                           float* __restrict__ qv, float* __restrict__ kv)
{
    int gw   = (blockIdx.x * 256 + threadIdx.x) >> 6;
    int lane = threadIdx.x & 63;
    bool isX = gw < BS * N;
    const float* src = isX ? (x + (size_t)gw * DIM) : (Wv + (size_t)(gw - BS * N) * DIM);
    u16*         dst = isX ? (xb + (size_t)gw * DIM) : (Wvb + (size_t)(gw - BS * N) * DIM);
    float qd = 0.f, kd = 0.f;
    #pragma unroll
    for (int i = 0; i < 4; ++i) {
        int e = i * 256 + lane * 4;
        float4 xv = *(const float4*)&src[e];
        uint2 p;
        p.x = (u32)f2bf(xv.x) | ((u32)f2bf(xv.y) << 16);
        p.y = (u32)f2bf(xv.z) | ((u32)f2bf(xv.w) << 16);
        *(uint2*)&dst[e] = p;
        if (isX) {
            float4 wq = *(const float4*)&Wq[e];
            float4 wk = *(const float4*)&Wk[e];
            qd += xv.x * wq.x + xv.y * wq.y + xv.z * wq.z + xv.w * wq.w;
            kd += xv.x * wk.x + xv.y * wk.y + xv.z * wk.z + xv.w * wk.w;
        }
    }
    if (isX) {
        #pragma unroll
        for (int off = 32; off; off >>= 1) {
            qd += __shfl_xor(qd, off);
            kd += __shfl_xor(kd, off);
        }
        if (lane == 0) { qv[gw] = qd + bq[0]; kv[gw] = kd + bk[0]; }
    }
}

// ---------------------------------------------------------------------------
// K2: attention writer + row-sum (replaces zker + old attker).
// One block per (batch, 16-row group). Pass 1: Z row sums; pass 2: fp32 att,
// float4 coalesced stores. Emits (q, invZ) pairs for the fused GEMM2.
__global__ void att_writer(const float* __restrict__ qv, const float* __restrict__ kvg,
                           float* __restrict__ att, float2* __restrict__ qzg)
{
    int blk = blockIdx.x;
    int b   = blk >> 6;
    int r0  = (blk & 63) * 16;
    __shared__ float ks[1024];
    int tid = threadIdx.x;
    #pragma unroll
    for (int i = 0; i < 4; ++i) ks[i * 256 + tid] = kvg[b * N + i * 256 + tid];
    int row = tid >> 4;          // 16 rows per block, 16 threads per row
    int c16 = tid & 15;
    float qrow = qv[b * N + r0 + row];
    __syncthreads();
    float z = 0.f;
    #pragma unroll 4
    for (int s = 0; s < 16; ++s) {
        const float4 kk = *(const float4*)&ks[(c16 + s * 16) * 4];
        z += __expf(qrow * kk.x) + __expf(qrow * kk.y)
           + __expf(qrow * kk.z) + __expf(qrow * kk.w);
    }
    z += __shfl_xor(z, 1); z += __shfl_xor(z, 2);
    z += __shfl_xor(z, 4); z += __shfl_xor(z, 8);
    float invZ = 1.0f / z;
    if (c16 == 0) qzg[b * N + r0 + row] = make_float2(qrow, invZ);
    float* ab = att + (size_t)b * N * N + (size_t)(r0 + row) * N;
    #pragma unroll 4
    for (int s = 0; s < 16; ++s) {
        int c0 = (c16 + s * 16) * 4;
        const float4 kk = *(const float4*)&ks[c0];
        float4 o;
        o.x = __expf(qrow * kk.x) * invZ;
        o.y = __expf(qrow * kk.y) * invZ;
        o.z = __expf(qrow * kk.z) * invZ;
        o.w = __expf(qrow * kk.w) * invZ;
        *(float4*)&ab[c0] = o;
    }
}

// ---------------------------------------------------------------------------
// K3: v[b] = Wv @ x[b]^T + bv.  C[b] = A (MxK rm) @ B[b]^T (NxK rm), bf16 out.
// m97 structure + XCD-aware swizzle (blk&7 = XCD; 4 whole batches per XCD).
__global__ __launch_bounds__(256) void gemm_bt(
    const u16* __restrict__ A,
    const u16* __restrict__ B, size_t bBatch,
    u16* __restrict__ C, size_t cBatch,
    const float* __restrict__ bias)
{
    const int K = 1024, LD = 1024;
    int blk  = blockIdx.x;
    int rest = blk >> 3;
    int b    = (blk & 7) * 4 + (rest >> 6);
    int t    = rest & 63;
    int m0  = (t >> 3) * 128, n0 = (t & 7) * 128;
    const u16* Ab = A;
    const u16* Bb = B + bBatch * (size_t)b;
    __shared__ u16 lA[128 * 32];
    __shared__ u16 lB[128 * 32];
    int w = threadIdx.x >> 6, lane = threadIdx.x & 63;
    int wr = (w >> 1) * 64, wc = (w & 1) * 64;
    int rowl = lane >> 2;
    int col8 = (lane & 3) * 8;
    int frow = lane & 15, fk = (lane >> 4) * 8;
    f32x4 acc[4][4] = {};

    for (int k0 = 0; k0 < K; k0 += 32) {
        #pragma unroll
        for (int s = 0; s < 2; ++s) {
            int rr = (s * 4 + w) * 16;
            async16(Ab + (size_t)(m0 + rr + rowl) * LD + k0 + col8, &lA[rr * 32]);
            async16(Bb + (size_t)(n0 + rr + rowl) * LD + k0 + col8, &lB[rr * 32]);
        }
        __syncthreads();
        bf16x8 af[4], bfr[4];
        #pragma unroll
        for (int i = 0; i < 4; ++i)
            af[i] = *(const bf16x8*)&lA[(wr + i * 16 + frow) * 32 + fk];
        #pragma unroll
        for (int j = 0; j < 4; ++j)
            bfr[j] = *(const bf16x8*)&lB[(wc + j * 16 + frow) * 32 + fk];
        #pragma unroll
        for (int i = 0; i < 4; ++i)
            #pragma unroll
            for (int j = 0; j < 4; ++j)
                acc[i][j] = __builtin_amdgcn_mfma_f32_16x16x32_bf16(af[i], bfr[j], acc[i][j], 0, 0, 0);
        __syncthreads();
    }

    int r4 = (lane >> 4) * 4, cc = lane & 15;
    u16* Cb = C + cBatch * (size_t)b;
    #pragma unroll
    for (int i = 0; i < 4; ++i)
        #pragma unroll
        for (int j = 0; j < 4; ++j)
            #pragma unroll
            for (int rg = 0; rg < 4; ++rg) {
                int row = m0 + wr + i * 16 + r4 + rg;
                int col = n0 + wc + j * 16 + cc;
                Cb[(size_t)row * LD + col] = f2bf(acc[i][j][rg] + bias[row]);
            }
}

// ---------------------------------------------------------------------------
// K4: out[b] = v[b] @ attn[b], with B = attn^T generated IN REGISTERS:
//   B[m][k] = exp(q_k * kv_m) * invZ_k  (rank-1 softmax -> no HBM B operand).
// A (vb) staged via global_load_lds; B-fragments computed under the vmcnt shadow.
__global__ __launch_bounds__(256) void gemm2_fused(
    const u16* __restrict__ A,          // vb: per-batch d x n bf16 row-major
    const float2* __restrict__ qzg,     // per-batch N of (q, invZ)
    const float* __restrict__ kvg,      // per-batch N of k
    float* __restrict__ C)              // out: per-batch d x m fp32 row-major
{
    const int K = 1024, LD = 1024;
    int blk  = blockIdx.x;
    int rest = blk >> 3;
    int b    = (blk & 7) * 4 + (rest >> 6);
    int t    = rest & 63;
    int m0  = (t >> 3) * 128, n0 = (t & 7) * 128;
    const u16* Ab = A + (size_t)b * K * LD;
    __shared__ u16   lA[128 * 32];
    __shared__ float2 qz[1024];
    int tid = threadIdx.x;
    int w = tid >> 6, lane = tid & 63;
    int wr = (w >> 1) * 64, wc = (w & 1) * 64;
    int rowl = lane >> 2;
    int col8 = (lane & 3) * 8;
    int frow = lane & 15, fk = (lane >> 4) * 8;

    const float2* qzb = qzg + (size_t)b * N;
    #pragma unroll
    for (int i = 0; i < 4; ++i) qz[i * 256 + tid] = qzb[i * 256 + tid];
    float kk[4];
    #pragma unroll
    for (int j = 0; j < 4; ++j) kk[j] = kvg[(size_t)b * N + n0 + wc + j * 16 + frow];
    f32x4 acc[4][4] = {};
    __syncthreads();

    for (int k0 = 0; k0 < K; k0 += 32) {
        #pragma unroll
        for (int s = 0; s < 2; ++s) {
            int rr = (s * 4 + w) * 16;
            async16(Ab + (size_t)(m0 + rr + rowl) * LD + k0 + col8, &lA[rr * 32]);
        }
        // B fragments in registers, computed while A loads are in flight.
        const float4* qsrc = (const float4*)&qz[k0 + fk];   // 8 (q,invZ) pairs
        float4 qp[4];
        #pragma unroll
        for (int u = 0; u < 4; ++u) qp[u] = qsrc[u];
        bf16x8 bfr[4];
        #pragma unroll
        for (int j = 0; j < 4; ++j) {
            union { u32 u[4]; bf16x8 v; } pk;
            #pragma unroll
            for (int u = 0; u < 4; ++u) {
                float e0 = __expf(qp[u].x * kk[j]) * qp[u].y;
                float e1 = __expf(qp[u].z * kk[j]) * qp[u].w;
                pk.u[u] = (u32)f2bf(e0) | ((u32)f2bf(e1) << 16);
            }
            bfr[j] = pk.v;
        }
        __syncthreads();
        bf16x8 af[4];
        #pragma unroll
        for (int i = 0; i < 4; ++i)
            af[i] = *(const bf16x8*)&lA[(wr + i * 16 + frow) * 32 + fk];
        #pragma unroll
        for (int i = 0; i < 4; ++i)
            #pragma unroll
            for (int j = 0; j < 4; ++j)
                acc[i][j] = __builtin_amdgcn_mfma_f32_16x16x32_bf16(af[i], bfr[j], acc[i][j], 0, 0, 0);
        __syncthreads();
    }

    int r4 = (lane >> 4) * 4, cc = lane & 15;
    float* Cb = C + (size_t)b * K * LD;
    #pragma unroll
    for (int i = 0; i < 4; ++i)
        #pragma unroll
        for (int j = 0; j < 4; ++j)
            #pragma unroll
            for (int rg = 0; rg < 4; ++rg) {
                int row = m0 + wr + i * 16 + r4 + rg;
                int col = n0 + wc + j * 16 + cc;
                Cb[(size_t)row * LD + col] = acc[i][j][rg];
            }
}

// ---------------------------------------------------------------------------
extern "C" void kernel_launch(void* const* d_in, const int* in_sizes, int n_in,
                              void* d_out, int out_size, void* d_ws, size_t ws_size,
                              hipStream_t stream)
{
    const float* x  = (const float*)d_in[0];
    const float* Wq = (const float*)d_in[1];
    const float* bq = (const float*)d_in[2];
    const float* Wk = (const float*)d_in[3];
    const float* bk = (const float*)d_in[4];
    const float* Wv = (const float*)d_in[5];
    const float* bv = (const float*)d_in[6];

    float* out = (float*)d_out;                 // (bs, n, d) raw-reshape of (bs, d, n)
    float* att = out + (size_t)BS * N * N;      // (bs, n, n)

    // Workspace layout (~131 MiB):
    char* ws = (char*)d_ws;
    u16*  xb   = (u16*)ws;                         // BS*N*DIM bf16
    u16*  vb   = xb + (size_t)BS * N * DIM;        // BS*DIM*N bf16
    u16*  Wvb  = vb + (size_t)BS * N * DIM;        // DIM*DIM bf16
    float* qv  = (float*)(Wvb + (size_t)DIM * DIM);
    float* kv  = qv + BS * N;
    float2* qzg = (float2*)(kv + BS * N);          // BS*N float2 (8B-aligned)

    convert_qk<<<(BS * N + DIM) / 4, 256, 0, stream>>>(x, Wq, bq, Wk, bk, Wv, xb, Wvb, qv, kv);
    att_writer<<<BS * 64, 256, 0, stream>>>(qv, kv, att, qzg);
    gemm_bt<<<BS * 64, 256, 0, stream>>>(Wvb, xb, (size_t)N * DIM, vb, (size_t)N * DIM, bv);
    gemm2_fused<<<BS * 64, 256, 0, stream>>>(vb, qzg, kv, out);
}